// Round 23
// baseline (225.000 us; speedup 1.0000x reference)
//
#include <hip/hip_runtime.h>
#include <hip/hip_bf16.h>

#define NN     10000
#define NE     320000
#define H1DIM  200
#define H1BST  208     /* h1 row stride (bf16 partials and bf16 h1) */
#define NCLS   8
#define NTST   2000
#define KDIM   10000
#define KPAD   10112   /* 158*64 */
#define KSPL   3
#define KSTEPS 26      /* 26*128*3 = 9984, +16-valid tail step on split 2 */
#define NGEMMB 471     /* 157 * KSPL */
#define DPAD   128     /* padded per-node edge slots */

typedef __bf16 bf16x8 __attribute__((ext_vector_type(8)));
typedef float  f32x4  __attribute__((ext_vector_type(4)));

__device__ __forceinline__ void load_lds16(const void* g, void* l) {
  __builtin_amdgcn_global_load_lds(
      (__attribute__((address_space(1))) void*)(void*)g,
      (__attribute__((address_space(3))) void*)l, 16, 0, 0);
}

/* ---------------- prep0: init + detect + W1 transpose (merged) ---------------- */

__global__ void k_prep0(float* deg, int* cnt, int* flags,
                        const unsigned* ei, const unsigned* mk, const unsigned* yy,
                        const float* __restrict__ W1, __bf16* __restrict__ Wt) {
  __shared__ float tile[64][65];
  __shared__ int s_f[4];
  int b = blockIdx.x, t = threadIdx.x;
  if (b < 40) {
    int i = b * 256 + t;
    if (i < NN) { deg[i] = 1.0f; cnt[i] = 0; }
    return;
  }
  if (b < 43) {
    unsigned a = 0;
    if (b == 40)      { for (int i = t; i < 2048; i += 256) a |= ei[2 * i + 1]; }
    else if (b == 41) { for (int i = t; i < 2048; i += 256) a |= yy[2 * i + 1]; }
    else              { for (int i = t; i < 900;  i += 256) a |= mk[2 * i + 1]; }
    int wid = t >> 6;
    int any = __any(a != 0) ? 1 : 0;
    if ((t & 63) == 0) s_f[wid] = any;
    __syncthreads();
    if (t == 0) {
      int f = s_f[0] | s_f[1] | s_f[2] | s_f[3];
      int idx = (b == 40) ? 0 : (b == 41) ? 2 : 1;
      flags[idx] = f;
    }
    return;
  }
  int bt = b - 43;                       /* 158 x 4 tiles, covers k<10112, n<256 */
  int k0 = (bt % 158) * 64, n0 = (bt / 158) * 64;
  int tn = t & 63, tk = t >> 6;
  for (int r = 0; r < 64; r += 4) {
    int k = k0 + tk + r, n = n0 + tn;
    tile[tk + r][tn] = (k < KDIM && n < H1DIM) ? W1[k * H1DIM + n] : 0.f;
  }
  __syncthreads();
  for (int r = 0; r < 64; r += 4) {
    int n = n0 + tk + r, k = k0 + tn;
    if (k < KPAD && n < 256)
      Wt[(size_t)n * KPAD + k] = (__bf16)tile[tn][tk + r];
  }
}

/* ------------- FUSED: GEMM1 (blocks < NGEMMB) + index convert/deg/slot-scatter.
   GEMM: h = x(f32->bf16) @ W1. NEW geometry: 64x256 tile, BK=128, 8 waves
   (wave tile 64x32, acc[4][2] = 32 VGPR), A rows staged as 512B contiguous
   DRAM runs (DRAM-page-granularity fix), Bs[2] halves so all B loads issue
   before ONE barrier -> 2 barriers per 128 cols. LDS 80KB -> 2 blocks/CU.
   K split 3-way -> 471 blocks = 92% of one residency round. ------------- */

__launch_bounds__(512, 4)
__global__ void k_gemm_cvt(const float* __restrict__ x, const __bf16* __restrict__ Wt,
                           __bf16* __restrict__ hpart,
                           const void* ei, const void* mk, const void* yy,
                           const float* __restrict__ ew, const int* __restrict__ flags,
                           int* idx32, int* mask32, int* y32, float* deg, int* cnt,
                           int* eids_pad) {
  int t = threadIdx.x;
  if (blockIdx.x >= NGEMMB) {
    int i = (blockIdx.x - NGEMMB) * 512 + t;
    if (i < NE) {
      int v = (flags[0] == 0) ? (int)((const long long*)ei)[i] : ((const int*)ei)[i];
      idx32[i] = min(max(v, 0), NN - 1);
    } else if (i < 2 * NE) {
      int v = (flags[0] == 0) ? (int)((const long long*)ei)[i] : ((const int*)ei)[i];
      v = min(max(v, 0), NN - 1);
      idx32[i] = v;
      atomicAdd(&deg[v], ew[i - NE]);
      int pos = atomicAdd(&cnt[v], 1);
      if (pos < DPAD) eids_pad[v * DPAD + pos] = i - NE;
    } else if (i < 2 * NE + NTST) {
      int j = i - 2 * NE;
      int v = (flags[1] == 0) ? (int)((const long long*)mk)[j] : ((const int*)mk)[j];
      mask32[j] = min(max(v, 0), NN - 1);
    } else if (i < 2 * NE + NTST + NN) {
      int j = i - 2 * NE - NTST;
      int v = (flags[2] == 0) ? (int)((const long long*)yy)[j] : ((const int*)yy)[j];
      y32[j] = min(max(v, 0), NN - 1);
    }
    return;
  }

  __shared__ __align__(16) __bf16 As[64 * 128];        /* 16 KB */
  __shared__ __align__(16) __bf16 Bs[2][256 * 64];     /* 64 KB */
  int wv = t >> 6, lane = t & 63;
  int wn = wv;                                  /* wave cols: wn*32 .. +31 */
  int m0 = (blockIdx.x % 157) * 64;
  int split = blockIdx.x / 157;
  int kbeg = split * (KSTEPS * 128);
  int nsteps = KSTEPS + ((split == KSPL - 1) ? 1 : 0);

  f32x4 acc[4][2];
  #pragma unroll
  for (int i = 0; i < 4; ++i)
    #pragma unroll
    for (int j = 0; j < 2; ++j)
      #pragma unroll
      for (int r = 0; r < 4; ++r) acc[i][j][r] = 0.f;

  /* A staging: row ar = t>>3 (64 rows), chunk acx = t&7 (16 f32 = 64B) */
  int ar = t >> 3;
  int acx = t & 7;
  long arow = m0 + ar; if (arow >= NN) arow = NN - 1;
  const float* aptr = x + (size_t)arow * KDIM + acx * 16;
  int ag0 = (2 * acx + 0) ^ (ar & 15);          /* 16 granules/row, 4-bit swizzle */
  int ag1 = (2 * acx + 1) ^ (ar & 15);
  __bf16* awr0 = As + ar * 128 + ag0 * 8;
  __bf16* awr1 = As + ar * 128 + ag1 * 8;

  /* B staging: per 64-col half, 2048 granules, 4 passes; linear dest,
     inverse-swizzled global source column */
  const __bf16* bsrc[4];
  int bdoff[4];
  #pragma unroll
  for (int pass = 0; pass < 4; ++pass) {
    int s = pass * 512 + t;
    int brow = s >> 3, bg = s & 7;
    bsrc[pass] = Wt + (size_t)brow * KPAD + ((bg ^ (brow & 7)) * 8);
    bdoff[pass] = (pass * 512 + wv * 64) * 8;
  }

  int lrow = lane & 15;
  int lhi = lane >> 4;
  int lx7 = lane & 7;

  float4 v0, v1, v2, v3;
  {
    bool pr = (kbeg + acx * 16 + 16 <= KDIM);
    if (pr) {
      const float4* p = (const float4*)(aptr + kbeg);
      v0 = p[0]; v1 = p[1]; v2 = p[2]; v3 = p[3];
    }
  }

  for (int ks = 0; ks < nsteps; ++ks) {
    int k0 = kbeg + ks * 128;
    /* issue ALL B loads for this step (both halves) */
    #pragma unroll
    for (int pass = 0; pass < 4; ++pass)
      load_lds16(bsrc[pass] + k0, (void*)(&Bs[0][0] + bdoff[pass]));
    #pragma unroll
    for (int pass = 0; pass < 4; ++pass)
      load_lds16(bsrc[pass] + k0 + 64, (void*)(&Bs[1][0] + bdoff[pass]));
    /* A cvt + swizzled write (128B/row contiguous source) */
    {
      bool pr = (k0 + acx * 16 + 16 <= KDIM);
      bf16x8 bva, bvb;
      if (pr) {
        bva[0] = (__bf16)v0.x; bva[1] = (__bf16)v0.y;
        bva[2] = (__bf16)v0.z; bva[3] = (__bf16)v0.w;
        bva[4] = (__bf16)v1.x; bva[5] = (__bf16)v1.y;
        bva[6] = (__bf16)v1.z; bva[7] = (__bf16)v1.w;
        bvb[0] = (__bf16)v2.x; bvb[1] = (__bf16)v2.y;
        bvb[2] = (__bf16)v2.z; bvb[3] = (__bf16)v2.w;
        bvb[4] = (__bf16)v3.x; bvb[5] = (__bf16)v3.y;
        bvb[6] = (__bf16)v3.z; bvb[7] = (__bf16)v3.w;
      } else {
        #pragma unroll
        for (int q = 0; q < 8; ++q) { bva[q] = (__bf16)0.f; bvb[q] = (__bf16)0.f; }
      }
      *(bf16x8*)awr0 = bva;
      *(bf16x8*)awr1 = bvb;
    }
    __syncthreads();

    if (ks + 1 < nsteps) {
      int k1 = k0 + 128;
      bool pr = (k1 + acx * 16 + 16 <= KDIM);
      if (pr) {
        const float4* p = (const float4*)(aptr + k1);
        v0 = p[0]; v1 = p[1]; v2 = p[2]; v3 = p[3];
      }
    }

    #pragma unroll
    for (int kk = 0; kk < 4; ++kk) {
      int gA = ((kk * 4 + lhi) ^ lrow) * 8;
      int gB = (((kk & 1) * 4 + lhi) ^ lx7) * 8;
      const __bf16* bbase = &Bs[kk >> 1][0];
      bf16x8 af[4], bf[2];
      #pragma unroll
      for (int i = 0; i < 4; ++i)
        af[i] = *(const bf16x8*)&As[(i * 16 + lrow) * 128 + gA];
      #pragma unroll
      for (int j = 0; j < 2; ++j)
        bf[j] = *(const bf16x8*)&bbase[(wn * 32 + j * 16 + lrow) * 64 + gB];
      #pragma unroll
      for (int i = 0; i < 4; ++i)
        #pragma unroll
        for (int j = 0; j < 2; ++j)
          acc[i][j] = __builtin_amdgcn_mfma_f32_16x16x32_bf16(af[i], bf[j], acc[i][j], 0, 0, 0);
    }
    __syncthreads();
  }

  __bf16* outp = hpart + (size_t)split * NN * H1BST;
  int colb = wn * 32 + (lane & 15);
  int rbase = m0 + ((lane >> 4) * 4);
  #pragma unroll
  for (int i = 0; i < 4; ++i)
    #pragma unroll
    for (int j = 0; j < 2; ++j) {
      int cg = colb + j * 16;
      if (cg < H1BST) {
        #pragma unroll
        for (int r = 0; r < 4; ++r) {
          int rg = rbase + i * 16 + r;
          if (rg < NN) outp[(size_t)rg * H1BST + cg] = (__bf16)acc[i][j][r];
        }
      }
    }
}

/* ------------- dis (block 254) + reduce bf16 partials -> h1b (blocks 0..253) ------------- */

__global__ void k_dis_red(const float* __restrict__ deg, float* dis,
                          const __bf16* __restrict__ hpart, __bf16* __restrict__ h1b) {
  int t = threadIdx.x;
  if (blockIdx.x == 254) {
    for (int base = 0; base < NN; base += 1024) {
      int idx = base + t;
      if (idx < NN) { float d = deg[idx]; dis[idx] = (d > 0.f) ? rsqrtf(d) : 0.f; }
    }
    return;
  }
  int i = blockIdx.x * 1024 + t;            /* i = c*26 + ch, 254*1024 >= 260000 */
  if (i < NN * 26) {
    int c = i / 26, ch = i - c * 26;
    size_t base = (size_t)c * H1BST + ch * 8;
    float s[8];
    #pragma unroll
    for (int q = 0; q < 8; ++q) s[q] = 0.f;
    #pragma unroll
    for (int sp = 0; sp < KSPL; ++sp) {
      bf16x8 v = *(const bf16x8*)(hpart + (size_t)sp * NN * H1BST + base);
      #pragma unroll
      for (int q = 0; q < 8; ++q) s[q] += (float)v[q];
    }
    bf16x8 o;
    #pragma unroll
    for (int q = 0; q < 8; ++q) o[q] = (__bf16)s[q];
    *(bf16x8*)&h1b[base] = o;
  }
}

/* ------------- agg1 (padded-slot gather, LDS-staged, factored dis_c)
   + bias + relu + W2 -> h2. len <= 128 so a single staged chunk. ------------- */

__global__ void k_agg1lin2(const __bf16* __restrict__ h1b, const float* __restrict__ dis,
                           const float* __restrict__ ew, const int* __restrict__ rows,
                           const int* __restrict__ cnt, const int* __restrict__ eids_pad,
                           const float* __restrict__ b1, const float* __restrict__ W2,
                           float* __restrict__ h2) {
  __shared__ int   s_r[DPAD];
  __shared__ float s_n[DPAD];
  __shared__ float s_acc[8][26][8];
  __shared__ float s_p[26][8];
  int c = blockIdx.x;
  int t = threadIdx.x;
  int len = min(cnt[c], DPAD);
  if (t < len) {
    int e = eids_pad[c * DPAD + t];
    int r = rows[e];
    s_r[t] = r;
    s_n[t] = ew[e] * dis[r];          /* partial norm; dis_c applied at finalize */
  }
  __syncthreads();

  int es = t >> 5;       /* 0..7 edge slot */
  int f8 = t & 31;       /* feature chunk, active when < 26 */
  float acc8[8];
  #pragma unroll
  for (int q = 0; q < 8; ++q) acc8[q] = 0.f;
  if (f8 < 26) {
    for (int j = es; j < len; j += 8) {
      float nv = s_n[j];
      bf16x8 v = *(const bf16x8*)&h1b[(size_t)s_r[j] * H1BST + f8 * 8];
      #pragma unroll
      for (int q = 0; q < 8; ++q) acc8[q] += nv * (float)v[q];
    }
    #pragma unroll
    for (int q = 0; q < 8; ++q) s_acc[es][f8][q] = acc8[q];
  }
  __syncthreads();

  if (es == 0 && f8 < 26) {
    bf16x8 selfv = *(const bf16x8*)&h1b[(size_t)c * H1BST + f8 * 8];
    float d = dis[c];
    float dd = d * d;
    float a[8];
    #pragma unroll
    for (int q = 0; q < 8; ++q) {
      float s = 0.f;
      #pragma unroll
      for (int e2 = 0; e2 < 8; ++e2) s += s_acc[e2][f8][q];
      int feat = f8 * 8 + q;
      if (feat < H1DIM) {
        float av = s * d + dd * (float)selfv[q] + b1[feat];
        a[q] = fmaxf(av, 0.f);
      } else {
        a[q] = 0.f;
      }
    }
    float p[8];
    #pragma unroll
    for (int o = 0; o < 8; ++o) p[o] = 0.f;
    #pragma unroll
    for (int q = 0; q < 8; ++q) {
      int feat = f8 * 8 + q;
      if (feat < H1DIM) {
        float4 wa = *(const float4*)&W2[feat * 8];
        float4 wb = *(const float4*)&W2[feat * 8 + 4];
        p[0] += a[q] * wa.x; p[1] += a[q] * wa.y;
        p[2] += a[q] * wa.z; p[3] += a[q] * wa.w;
        p[4] += a[q] * wb.x; p[5] += a[q] * wb.y;
        p[6] += a[q] * wb.z; p[7] += a[q] * wb.w;
      }
    }
    #pragma unroll
    for (int o = 0; o < 8; ++o) s_p[f8][o] = p[o];
  }
  __syncthreads();

  if (t < 8) {
    float s = 0.f;
    #pragma unroll
    for (int q = 0; q < 26; ++q) s += s_p[q][t];
    h2[(size_t)c * 8 + t] = s;
  }
}

/* ------------- aggregation 2 ONLY for masked nodes (padded slots), fused out ------------- */

__global__ void k_agg2out(const float* __restrict__ h2, const float* __restrict__ dis,
                          const float* __restrict__ ew, const int* __restrict__ rows,
                          const int* __restrict__ cnt, const int* __restrict__ eids_pad,
                          const float* __restrict__ b2, const int* __restrict__ mask,
                          const int* __restrict__ yv, float* __restrict__ out) {
  int i = blockIdx.x * 256 + threadIdx.x;
  if (i < NTST * NCLS) {
    int r = i >> 3, o = i & 7;
    int c = mask[r];
    float d = dis[c];
    float acc = 0.f;
    int len = min(cnt[c], DPAD);
    for (int j = 0; j < len; ++j) {
      int e = eids_pad[c * DPAD + j];
      int rr = rows[e];
      acc += ew[e] * dis[rr] * h2[rr * NCLS + o];
    }
    out[i] = acc * d + d * d * h2[c * NCLS + o] + b2[o];
  } else if (i < NTST * NCLS + NTST) {
    int r = i - NTST * NCLS;
    out[i] = (float)yv[mask[r]];
  }
}

/* ---------------- host ---------------- */

extern "C" void kernel_launch(void* const* d_in, const int* in_sizes, int n_in,
                              void* d_out, int out_size, void* d_ws, size_t ws_size,
                              hipStream_t stream) {
  const float* x    = (const float*)d_in[0];
  const void*  ei   = d_in[1];
  const float* ew   = (const float*)d_in[2];
  const void*  mask = d_in[3];
  const void*  y    = d_in[4];
  const float* W1   = (const float*)d_in[5];
  const float* b1   = (const float*)d_in[6];
  const float* W2   = (const float*)d_in[7];
  const float* b2   = (const float*)d_in[8];
  float* out = (float*)d_out;

  char* ws = (char*)d_ws;
  float* deg    = (float*)(ws + 0);                         /* 40 KB   */
  float* dis    = (float*)(ws + (64 << 10));                /* 40 KB   */
  int*   idx32  = (int*)(ws + (2 << 20));                   /* 2.56 MB */
  float* h2     = (float*)(ws + (5 << 20));                 /* 320 KB  */
  int*   mask32 = (int*)(ws + (6 << 20));                   /* 8 KB    */
  int*   y32    = (int*)(ws + (6 << 20) + (64 << 10));      /* 40 KB   */
  int*   flags  = (int*)(ws + (6 << 20) + (128 << 10));     /* 16 B    */
  int*   cnt    = (int*)(ws + (6 << 20) + (256 << 10));     /* 40 KB   */
  __bf16* Wt    = (__bf16*)(ws + ((size_t)9 << 20));        /* 5.18 MB */
  __bf16* h1b   = (__bf16*)(ws + ((size_t)16 << 20));       /* 4.16 MB */
  __bf16* hpart = (__bf16*)(ws + ((size_t)24 << 20));       /* 3 x 4.16 MB = 12.5 MB */
  int* eids_pad = (int*)(ws + ((size_t)52 << 20));          /* 5.12 MB */

  int* rows32 = idx32;

  k_prep0<<<dim3(675), dim3(256), 0, stream>>>(deg, cnt, flags,
                                               (const unsigned*)ei, (const unsigned*)mask,
                                               (const unsigned*)y, W1, Wt);

  /* gemm (471 blocks) + convert/degree/slot-scatter (1274 blocks), co-scheduled */
  k_gemm_cvt<<<dim3(NGEMMB + 1274), dim3(512), 0, stream>>>(
      x, Wt, hpart, ei, mask, y, ew, flags, idx32, mask32, y32, deg, cnt, eids_pad);

  /* dis (block 254) + partial-reduce/cvt (blocks 0..253), co-scheduled */
  k_dis_red<<<dim3(255), dim3(1024), 0, stream>>>(deg, dis, hpart, h1b);

  k_agg1lin2<<<dim3(10000), dim3(256), 0, stream>>>(h1b, dis, ew, rows32, cnt, eids_pad,
                                                    b1, W2, h2);
  k_agg2out<<<dim3(71), dim3(256), 0, stream>>>(h2, dis, ew, rows32, cnt, eids_pad, b2,
                                                mask32, y32, out);
}

// Round 24
// 223.321 us; speedup vs baseline: 1.0075x; 1.0075x over previous
//
#include <hip/hip_runtime.h>
#include <hip/hip_bf16.h>

#define NN     10000
#define NE     320000
#define H1DIM  200
#define H1BST  208     /* h1 row stride (bf16 partials and bf16 h1) */
#define NCLS   8
#define NTST   2000
#define KDIM   10000
#define KPAD   10048   /* 157*64 */
#define KSPL   6
#define KSTEPS 26      /* 26*64*6 = 9984, +64-pad tail step on split 5 */
#define NGEMMB 474     /* 79 * KSPL */
#define DPAD   128     /* padded per-node edge slots */

typedef __bf16 bf16x8 __attribute__((ext_vector_type(8)));
typedef float  f32x4  __attribute__((ext_vector_type(4)));

__device__ __forceinline__ void load_lds16(const void* g, void* l) {
  __builtin_amdgcn_global_load_lds(
      (__attribute__((address_space(1))) void*)(void*)g,
      (__attribute__((address_space(3))) void*)l, 16, 0, 0);
}

/* ---------------- prep0: init + detect + W1 transpose (merged) ---------------- */

__global__ void k_prep0(float* deg, int* cnt, int* flags,
                        const unsigned* ei, const unsigned* mk, const unsigned* yy,
                        const float* __restrict__ W1, __bf16* __restrict__ Wt) {
  __shared__ float tile[64][65];
  __shared__ int s_f[4];
  int b = blockIdx.x, t = threadIdx.x;
  if (b < 40) {
    int i = b * 256 + t;
    if (i < NN) { deg[i] = 1.0f; cnt[i] = 0; }
    return;
  }
  if (b < 43) {
    unsigned a = 0;
    if (b == 40)      { for (int i = t; i < 2048; i += 256) a |= ei[2 * i + 1]; }
    else if (b == 41) { for (int i = t; i < 2048; i += 256) a |= yy[2 * i + 1]; }
    else              { for (int i = t; i < 900;  i += 256) a |= mk[2 * i + 1]; }
    int wid = t >> 6;
    int any = __any(a != 0) ? 1 : 0;
    if ((t & 63) == 0) s_f[wid] = any;
    __syncthreads();
    if (t == 0) {
      int f = s_f[0] | s_f[1] | s_f[2] | s_f[3];
      int idx = (b == 40) ? 0 : (b == 41) ? 2 : 1;
      flags[idx] = f;
    }
    return;
  }
  int bt = b - 43;                       /* 157 x 4 tiles, covers k<10048, n<256 */
  int k0 = (bt % 157) * 64, n0 = (bt / 157) * 64;
  int tn = t & 63, tk = t >> 6;
  for (int r = 0; r < 64; r += 4) {
    int k = k0 + tk + r, n = n0 + tn;
    tile[tk + r][tn] = (k < KDIM && n < H1DIM) ? W1[k * H1DIM + n] : 0.f;
  }
  __syncthreads();
  for (int r = 0; r < 64; r += 4) {
    int n = n0 + tk + r, k = k0 + tn;
    if (k < KPAD && n < 256)
      Wt[(size_t)n * KPAD + k] = (__bf16)tile[tn][tk + r];
  }
}

/* ------------- FUSED: GEMM1 (blocks < NGEMMB) + index convert/deg/slot-scatter.
   GEMM: h = x(f32->bf16) @ W1, 128x256 tile, BK=64, 8 waves, 48KB LDS,
   8-granule XOR swizzle, K split 6-way, bf16 partial stores.
   cvt lane: idx convert + degree atomics + eids_pad[c][slot] scatter (slot =
   atomicAdd(cnt) return) -- replaces the prefix-scan + CSR-scatter kernels. ------------- */

__launch_bounds__(512, 4)
__global__ void k_gemm_cvt(const float* __restrict__ x, const __bf16* __restrict__ Wt,
                           __bf16* __restrict__ hpart,
                           const void* ei, const void* mk, const void* yy,
                           const float* __restrict__ ew, const int* __restrict__ flags,
                           int* idx32, int* mask32, int* y32, float* deg, int* cnt,
                           int* eids_pad) {
  int t = threadIdx.x;
  if (blockIdx.x >= NGEMMB) {
    int i = (blockIdx.x - NGEMMB) * 512 + t;
    if (i < NE) {
      int v = (flags[0] == 0) ? (int)((const long long*)ei)[i] : ((const int*)ei)[i];
      idx32[i] = min(max(v, 0), NN - 1);
    } else if (i < 2 * NE) {
      int v = (flags[0] == 0) ? (int)((const long long*)ei)[i] : ((const int*)ei)[i];
      v = min(max(v, 0), NN - 1);
      idx32[i] = v;
      atomicAdd(&deg[v], ew[i - NE]);
      int pos = atomicAdd(&cnt[v], 1);
      if (pos < DPAD) eids_pad[v * DPAD + pos] = i - NE;
    } else if (i < 2 * NE + NTST) {
      int j = i - 2 * NE;
      int v = (flags[1] == 0) ? (int)((const long long*)mk)[j] : ((const int*)mk)[j];
      mask32[j] = min(max(v, 0), NN - 1);
    } else if (i < 2 * NE + NTST + NN) {
      int j = i - 2 * NE - NTST;
      int v = (flags[2] == 0) ? (int)((const long long*)yy)[j] : ((const int*)yy)[j];
      y32[j] = min(max(v, 0), NN - 1);
    }
    return;
  }

  __shared__ __align__(16) __bf16 As[128 * 64];   /* 16 KB */
  __shared__ __align__(16) __bf16 Bs[256 * 64];   /* 32 KB */
  int wv = t >> 6, lane = t & 63;
  int wm = wv >> 2, wn = wv & 3;
  int m0 = (blockIdx.x % 79) * 128;
  int split = blockIdx.x / 79;
  int kbeg = split * (KSTEPS * 64);
  int nsteps = KSTEPS + ((split == KSPL - 1) ? 1 : 0);

  f32x4 acc[4][4];
  #pragma unroll
  for (int i = 0; i < 4; ++i)
    #pragma unroll
    for (int j = 0; j < 4; ++j)
      #pragma unroll
      for (int r = 0; r < 4; ++r) acc[i][j][r] = 0.f;

  int am = t >> 2;
  int ac = t & 3;
  long arow = m0 + am; if (arow >= NN) arow = NN - 1;
  const float* aptr = x + (size_t)arow * KDIM + ac * 16;
  int ag0 = (2 * ac + 0) ^ (am & 7);
  int ag1 = (2 * ac + 1) ^ (am & 7);
  __bf16* awr0 = As + am * 64 + ag0 * 8;
  __bf16* awr1 = As + am * 64 + ag1 * 8;

  const __bf16* bsrc[4];
  __bf16* bdst[4];
  #pragma unroll
  for (int pass = 0; pass < 4; ++pass) {
    int s = pass * 512 + t;
    int brow = s >> 3, bg = s & 7;
    bsrc[pass] = Wt + (size_t)brow * KPAD + ((bg ^ (brow & 7)) * 8);
    bdst[pass] = Bs + (size_t)(pass * 512 + wv * 64) * 8;
  }

  int lrow = lane & 15;
  int lhi = lane >> 4;
  int lx7 = lane & 7;

  float4 v0, v1, v2, v3;
  {
    bool pr = (kbeg + ac * 16 + 16 <= KDIM);
    if (pr) {
      const float4* p = (const float4*)(aptr + kbeg);
      v0 = p[0]; v1 = p[1]; v2 = p[2]; v3 = p[3];
    }
  }

  for (int ks = 0; ks < nsteps; ++ks) {
    int k0 = kbeg + ks * 64;
    #pragma unroll
    for (int pass = 0; pass < 4; ++pass)
      load_lds16(bsrc[pass] + k0, bdst[pass]);
    {
      bool pr = (k0 + ac * 16 + 16 <= KDIM);
      bf16x8 bva, bvb;
      if (pr) {
        bva[0] = (__bf16)v0.x; bva[1] = (__bf16)v0.y;
        bva[2] = (__bf16)v0.z; bva[3] = (__bf16)v0.w;
        bva[4] = (__bf16)v1.x; bva[5] = (__bf16)v1.y;
        bva[6] = (__bf16)v1.z; bva[7] = (__bf16)v1.w;
        bvb[0] = (__bf16)v2.x; bvb[1] = (__bf16)v2.y;
        bvb[2] = (__bf16)v2.z; bvb[3] = (__bf16)v2.w;
        bvb[4] = (__bf16)v3.x; bvb[5] = (__bf16)v3.y;
        bvb[6] = (__bf16)v3.z; bvb[7] = (__bf16)v3.w;
      } else {
        #pragma unroll
        for (int q = 0; q < 8; ++q) { bva[q] = (__bf16)0.f; bvb[q] = (__bf16)0.f; }
      }
      *(bf16x8*)awr0 = bva;
      *(bf16x8*)awr1 = bvb;
    }
    __syncthreads();

    if (ks + 1 < nsteps) {
      int k1 = k0 + 64;
      bool pr = (k1 + ac * 16 + 16 <= KDIM);
      if (pr) {
        const float4* p = (const float4*)(aptr + k1);
        v0 = p[0]; v1 = p[1]; v2 = p[2]; v3 = p[3];
      }
    }

    #pragma unroll
    for (int kk = 0; kk < 2; ++kk) {
      int gs8 = ((kk * 4 + lhi) ^ lx7) * 8;
      bf16x8 af[4], bf[4];
      #pragma unroll
      for (int i = 0; i < 4; ++i)
        af[i] = *(const bf16x8*)&As[(wm * 64 + i * 16 + lrow) * 64 + gs8];
      #pragma unroll
      for (int j = 0; j < 4; ++j)
        bf[j] = *(const bf16x8*)&Bs[(wn * 64 + j * 16 + lrow) * 64 + gs8];
      #pragma unroll
      for (int i = 0; i < 4; ++i)
        #pragma unroll
        for (int j = 0; j < 4; ++j)
          acc[i][j] = __builtin_amdgcn_mfma_f32_16x16x32_bf16(af[i], bf[j], acc[i][j], 0, 0, 0);
    }
    __syncthreads();
  }

  __bf16* outp = hpart + (size_t)split * NN * H1BST;
  int colb = wn * 64 + (lane & 15);
  int rbase = m0 + wm * 64 + ((lane >> 4) * 4);
  #pragma unroll
  for (int i = 0; i < 4; ++i)
    #pragma unroll
    for (int j = 0; j < 4; ++j) {
      int cg = colb + j * 16;
      if (cg < H1BST) {
        #pragma unroll
        for (int r = 0; r < 4; ++r) {
          int rg = rbase + i * 16 + r;
          if (rg < NN) outp[(size_t)rg * H1BST + cg] = (__bf16)acc[i][j][r];
        }
      }
    }
}

/* ------------- dis (block 254) + reduce bf16 partials -> h1b (blocks 0..253) ------------- */

__global__ void k_dis_red(const float* __restrict__ deg, float* dis,
                          const __bf16* __restrict__ hpart, __bf16* __restrict__ h1b) {
  int t = threadIdx.x;
  if (blockIdx.x == 254) {
    for (int base = 0; base < NN; base += 1024) {
      int idx = base + t;
      if (idx < NN) { float d = deg[idx]; dis[idx] = (d > 0.f) ? rsqrtf(d) : 0.f; }
    }
    return;
  }
  int i = blockIdx.x * 1024 + t;            /* i = c*26 + ch, 254*1024 >= 260000 */
  if (i < NN * 26) {
    int c = i / 26, ch = i - c * 26;
    size_t base = (size_t)c * H1BST + ch * 8;
    float s[8];
    #pragma unroll
    for (int q = 0; q < 8; ++q) s[q] = 0.f;
    #pragma unroll
    for (int sp = 0; sp < KSPL; ++sp) {
      bf16x8 v = *(const bf16x8*)(hpart + (size_t)sp * NN * H1BST + base);
      #pragma unroll
      for (int q = 0; q < 8; ++q) s[q] += (float)v[q];
    }
    bf16x8 o;
    #pragma unroll
    for (int q = 0; q < 8; ++q) o[q] = (__bf16)s[q];
    *(bf16x8*)&h1b[base] = o;
  }
}

/* ------------- agg1 (padded-slot gather, LDS-staged, factored dis_c)
   + bias + relu + W2 -> h2. len <= 128 so a single staged chunk. ------------- */

__global__ void k_agg1lin2(const __bf16* __restrict__ h1b, const float* __restrict__ dis,
                           const float* __restrict__ ew, const int* __restrict__ rows,
                           const int* __restrict__ cnt, const int* __restrict__ eids_pad,
                           const float* __restrict__ b1, const float* __restrict__ W2,
                           float* __restrict__ h2) {
  __shared__ int   s_r[DPAD];
  __shared__ float s_n[DPAD];
  __shared__ float s_acc[8][26][8];
  __shared__ float s_p[26][8];
  int c = blockIdx.x;
  int t = threadIdx.x;
  int len = min(cnt[c], DPAD);
  if (t < len) {
    int e = eids_pad[c * DPAD + t];
    int r = rows[e];
    s_r[t] = r;
    s_n[t] = ew[e] * dis[r];          /* partial norm; dis_c applied at finalize */
  }
  __syncthreads();

  int es = t >> 5;       /* 0..7 edge slot */
  int f8 = t & 31;       /* feature chunk, active when < 26 */
  float acc8[8];
  #pragma unroll
  for (int q = 0; q < 8; ++q) acc8[q] = 0.f;
  if (f8 < 26) {
    for (int j = es; j < len; j += 8) {
      float nv = s_n[j];
      bf16x8 v = *(const bf16x8*)&h1b[(size_t)s_r[j] * H1BST + f8 * 8];
      #pragma unroll
      for (int q = 0; q < 8; ++q) acc8[q] += nv * (float)v[q];
    }
    #pragma unroll
    for (int q = 0; q < 8; ++q) s_acc[es][f8][q] = acc8[q];
  }
  __syncthreads();

  if (es == 0 && f8 < 26) {
    bf16x8 selfv = *(const bf16x8*)&h1b[(size_t)c * H1BST + f8 * 8];
    float d = dis[c];
    float dd = d * d;
    float a[8];
    #pragma unroll
    for (int q = 0; q < 8; ++q) {
      float s = 0.f;
      #pragma unroll
      for (int e2 = 0; e2 < 8; ++e2) s += s_acc[e2][f8][q];
      int feat = f8 * 8 + q;
      if (feat < H1DIM) {
        float av = s * d + dd * (float)selfv[q] + b1[feat];
        a[q] = fmaxf(av, 0.f);
      } else {
        a[q] = 0.f;
      }
    }
    float p[8];
    #pragma unroll
    for (int o = 0; o < 8; ++o) p[o] = 0.f;
    #pragma unroll
    for (int q = 0; q < 8; ++q) {
      int feat = f8 * 8 + q;
      if (feat < H1DIM) {
        float4 wa = *(const float4*)&W2[feat * 8];
        float4 wb = *(const float4*)&W2[feat * 8 + 4];
        p[0] += a[q] * wa.x; p[1] += a[q] * wa.y;
        p[2] += a[q] * wa.z; p[3] += a[q] * wa.w;
        p[4] += a[q] * wb.x; p[5] += a[q] * wb.y;
        p[6] += a[q] * wb.z; p[7] += a[q] * wb.w;
      }
    }
    #pragma unroll
    for (int o = 0; o < 8; ++o) s_p[f8][o] = p[o];
  }
  __syncthreads();

  if (t < 8) {
    float s = 0.f;
    #pragma unroll
    for (int q = 0; q < 26; ++q) s += s_p[q][t];
    h2[(size_t)c * 8 + t] = s;
  }
}

/* ------------- aggregation 2 ONLY for masked nodes (padded slots), fused out ------------- */

__global__ void k_agg2out(const float* __restrict__ h2, const float* __restrict__ dis,
                          const float* __restrict__ ew, const int* __restrict__ rows,
                          const int* __restrict__ cnt, const int* __restrict__ eids_pad,
                          const float* __restrict__ b2, const int* __restrict__ mask,
                          const int* __restrict__ yv, float* __restrict__ out) {
  int i = blockIdx.x * 256 + threadIdx.x;
  if (i < NTST * NCLS) {
    int r = i >> 3, o = i & 7;
    int c = mask[r];
    float d = dis[c];
    float acc = 0.f;
    int len = min(cnt[c], DPAD);
    for (int j = 0; j < len; ++j) {
      int e = eids_pad[c * DPAD + j];
      int rr = rows[e];
      acc += ew[e] * dis[rr] * h2[rr * NCLS + o];
    }
    out[i] = acc * d + d * d * h2[c * NCLS + o] + b2[o];
  } else if (i < NTST * NCLS + NTST) {
    int r = i - NTST * NCLS;
    out[i] = (float)yv[mask[r]];
  }
}

/* ---------------- host ---------------- */

extern "C" void kernel_launch(void* const* d_in, const int* in_sizes, int n_in,
                              void* d_out, int out_size, void* d_ws, size_t ws_size,
                              hipStream_t stream) {
  const float* x    = (const float*)d_in[0];
  const void*  ei   = d_in[1];
  const float* ew   = (const float*)d_in[2];
  const void*  mask = d_in[3];
  const void*  y    = d_in[4];
  const float* W1   = (const float*)d_in[5];
  const float* b1   = (const float*)d_in[6];
  const float* W2   = (const float*)d_in[7];
  const float* b2   = (const float*)d_in[8];
  float* out = (float*)d_out;

  char* ws = (char*)d_ws;
  float* deg    = (float*)(ws + 0);                         /* 40 KB   */
  float* dis    = (float*)(ws + (64 << 10));                /* 40 KB   */
  int*   idx32  = (int*)(ws + (2 << 20));                   /* 2.56 MB */
  float* h2     = (float*)(ws + (5 << 20));                 /* 320 KB  */
  int*   mask32 = (int*)(ws + (6 << 20));                   /* 8 KB    */
  int*   y32    = (int*)(ws + (6 << 20) + (64 << 10));      /* 40 KB   */
  int*   flags  = (int*)(ws + (6 << 20) + (128 << 10));     /* 16 B    */
  int*   cnt    = (int*)(ws + (6 << 20) + (256 << 10));     /* 40 KB   */
  __bf16* Wt    = (__bf16*)(ws + ((size_t)9 << 20));        /* 5.15 MB */
  __bf16* h1b   = (__bf16*)(ws + ((size_t)16 << 20));       /* 4.16 MB */
  __bf16* hpart = (__bf16*)(ws + ((size_t)24 << 20));       /* 6 x 4.16 MB = 25 MB */
  int* eids_pad = (int*)(ws + ((size_t)52 << 20));          /* 5.12 MB */

  int* rows32 = idx32;

  k_prep0<<<dim3(671), dim3(256), 0, stream>>>(deg, cnt, flags,
                                               (const unsigned*)ei, (const unsigned*)mask,
                                               (const unsigned*)y, W1, Wt);

  /* gemm (474 blocks) + convert/degree/slot-scatter (1274 blocks), co-scheduled */
  k_gemm_cvt<<<dim3(NGEMMB + 1274), dim3(512), 0, stream>>>(
      x, Wt, hpart, ei, mask, y, ew, flags, idx32, mask32, y32, deg, cnt, eids_pad);

  /* dis (block 254) + partial-reduce/cvt (blocks 0..253), co-scheduled */
  k_dis_red<<<dim3(255), dim3(1024), 0, stream>>>(deg, dis, hpart, h1b);

  k_agg1lin2<<<dim3(10000), dim3(256), 0, stream>>>(h1b, dis, ew, rows32, cnt, eids_pad,
                                                    b1, W2, h2);
  k_agg2out<<<dim3(71), dim3(256), 0, stream>>>(h2, dis, ew, rows32, cnt, eids_pad, b2,
                                                mask32, y32, out);
}